// Round 9
// baseline (1069.581 us; speedup 1.0000x reference)
//
#include <hip/hip_runtime.h>
#include <math.h>

#define BS   256
#define NN   255
#define DIM  128
#define GAMMA 0.07
#define NUM_ITERS 1000

typedef float v2f __attribute__((ext_vector_type(2)));

__device__ __forceinline__ double wred_d(double v) {
  #pragma unroll
  for (int k = 1; k < 64; k <<= 1) v += __shfl_xor(v, k, 64);
  return v;
}
__device__ __forceinline__ int wred_i(int v) {
  #pragma unroll
  for (int k = 1; k < 64; k <<= 1) v += __shfl_xor(v, k, 64);
  return v;
}

// DPP add: x += value from DPP-selected lane (bound_ctrl=0-fill)
template <int CTRL, int RMASK>
__device__ __forceinline__ float dpp_add(float x) {
  int t = __builtin_amdgcn_update_dpp(0, __float_as_int(x), CTRL, RMASK, 0xf, true);
  return x + __int_as_float(t);
}

// ---- pure-VALU xor-butterfly add levels over the band index m=l>>3 ----
// (R20/R21-validated, absmax 0): pairing ((m0+m1)+(m2+m3))+((m4+m5)+(m6+m7))
__device__ __forceinline__ float bfly8(float x) {
  int t = __builtin_amdgcn_update_dpp(0, __float_as_int(x), 0x128, 0xf, 0xf, true);
  return x + __int_as_float(t);   // row_ror:8 == l^8 within 16-lane rows
}
__device__ __forceinline__ float bfly16(float x) {
#if __has_builtin(__builtin_amdgcn_permlane16_swap)
  unsigned u = __float_as_uint(x);
  auto p = __builtin_amdgcn_permlane16_swap(u, u, false, false);
  return __uint_as_float(p[0]) + __uint_as_float(p[1]);
#else
  return x + __shfl_xor(x, 16, 64);
#endif
}
__device__ __forceinline__ float bfly32(float x) {
#if __has_builtin(__builtin_amdgcn_permlane32_swap)
  unsigned u = __float_as_uint(x);
  auto p = __builtin_amdgcn_permlane32_swap(u, u, false, false);
  return __uint_as_float(p[0]) + __uint_as_float(p[1]);
#else
  return x + __shfl_xor(x, 32, 64);
#endif
}

// fast reciprocal-sqrt: v_rsq_f32 + one Newton step (~0.5 ulp)
__device__ __forceinline__ float rsq_nr(float x) {
  float r;
  asm("v_rsq_f32 %0, %1" : "=v"(r) : "v"(x));
  r = r * (1.5f - 0.5f * x * r * r);
  return r;
}

// packed dual-fp32 FMA (VOP3P): acc.lo += k.lo*y.lo; acc.hi += k.hi*y.hi
__device__ __forceinline__ void pk_fma(v2f& acc, const v2f& k, const v2f& y) {
  asm("v_pk_fma_f32 %0, %1, %2, %0" : "+v"(acc) : "v"(k), "v"(y));
}

// ---------------- kernel 1: normalized features, stored transposed fp64 ----------------
__global__ void k_ftr(const float* __restrict__ z, double* __restrict__ ftrT) {
  int b = blockIdx.x;
  int d = threadIdx.x;
  double z0 = (double)z[b * 256 + d];
  double z1 = (double)z[b * 256 + 128 + d];
  double n = sqrt(z0 * z0 + z1 * z1);
  n = fmax(n, 1e-12);
  ftrT[d * 512 + b]       = z0 / n;
  ftrT[d * 512 + 256 + b] = z1 / n;
}

// ---------------- kernel 2: K = exp(-gamma * dist), fp64 math, fp32 store ----------------
__global__ void k_K(const double* __restrict__ ftrT, float* __restrict__ K,
                    double* __restrict__ pk_knt, double* __restrict__ pos_arr) {
  int i = blockIdx.x;
  int t = threadIdx.x;
  __shared__ double rowi[DIM];
  __shared__ double redd[4];
  if (t < DIM) rowi[t] = ftrT[t * 512 + i];
  __syncthreads();
  double xn = 0.0;
  #pragma unroll 8
  for (int d = 0; d < DIM; ++d) xn += rowi[d] * rowi[d];

  double knt_part = 0.0;
  #pragma unroll
  for (int h = 0; h < 2; ++h) {
    int j = t + h * 256;
    double dot = 0.0, sq = 0.0;
    #pragma unroll 8
    for (int d = 0; d < DIM; ++d) {
      double f = ftrT[d * 512 + j];
      dot += rowi[d] * f;
      sq  += f * f;
    }
    double dist = xn + sq - 2.0 * dot;
    double kv = exp(-GAMMA * dist);
    K[i * 512 + j] = (float)kv;
    if (h == 1) {
      if (j == 256 + i) pos_arr[i] = kv;
      else knt_part += kv;
    }
  }
  double w = wred_d(knt_part);
  if ((t & 63) == 0) redd[t >> 6] = w;
  __syncthreads();
  if (t == 0) pk_knt[i] = redd[0] + redd[1] + redd[2] + redd[3];
}

// ---------------- kernel 3: per-batch PGD — R23: distributed phase B ----------------
// Matvec stays row-owned (R15-exact: wave rg = rows [32rg,32rg+32), lane l =
// cols 4l..4l+3). Solver state is now COLUMN-owned: wave rg owns cols
// [32rg,32rg+32); lane l holds quad c0=32rg+4*(l&7) (replicated over l>>3).
// Per iteration (still 2 barriers, but both windows are all-wave parallel):
//   A: matvec -> part[rg][:] (part stride 264: read pattern is 2-way = free)
//   B1
//   C: Sv = tree over 8 Sy scalars (exact wred64_dpp decomposition:
//      ((S7+S6)+(S5+S4))+((S3+S2)+(S1+S0)), per-wave T8 via 3 DPP row_shr);
//      gr = 8 bcast reads part[m][r] + R15 add4-order tree; gA = own-cols
//      slice of part + xor8/16/32 butterfly over bands (R21-validated);
//      g, s=(g0²+g1²)+(g2²+g3²), P_rg = T8 shr-tree (lane 7 publishes).
//   B2
//   D: n2 = ((P7+P6)+(P5+P4))+((P3+P2)+(P1+P0)) (exact tree), sinv, update
//      own cols, write OWN ytil slice (same-wave RAW for next matvec — the
//      old post-B2 y-broadcast round trip is gone), publish Sy_rg.
// Every reduction tree reproduces the session-validated pairing exactly
// (commutativity covers operand order) -> bit-exact, absmax must stay 0.
// Lessons enforced: no replication of whole phase B (R16/17/21), no flags
// (R19), no LDS atomics (R15), occupancy not the limiter (R18).
__global__ __launch_bounds__(512, 2) void k_pgd(
    const float* __restrict__ K, const float* __restrict__ alpha_init,
    double* __restrict__ neg_arr, double* __restrict__ sa_arr,
    int* __restrict__ cnt1, int* __restrict__ cntp, int* __restrict__ cnt0) {
  int r = blockIdx.x;
  int tid = threadIdx.x;
  int l = tid & 63;
  int rg = tid >> 6;        // wave: row band for MV, col group for solve

  __shared__ __align__(16) float part[8][264];  // stride 264: 8m+4k banks -> 2-way max
  __shared__ __align__(16) float ytil[BS];      // a-indexed, ytil[r]==0 always
  __shared__ float betat[1024];
  __shared__ float P_lds[8];                    // per-wave n2 partials
  __shared__ float Sy_lds[8];                   // per-wave y-sum partials
  __shared__ double dred[2][8];
  __shared__ int ired[3][8];

  // beta table: betat[i] = i/(i+3) fp32 (read at index it+1)
  for (int i = tid; i < 1024; i += 512)
    betat[i] = (float)i / ((float)i + 3.0f);

  // MV staging (R15-exact): kq[16k+j] = (K[32rg+2j][4l+k], K[32rg+2j+1][4l+k])
  v2f kq[64];
  #pragma unroll
  for (int j = 0; j < 16; ++j) {
    float4 r0 = *(const float4*)&K[(32 * rg + 2 * j + 0) * 512 + 4 * l];
    float4 r1 = *(const float4*)&K[(32 * rg + 2 * j + 1) * 512 + 4 * l];
    kq[j].x      = r0.x; kq[j].y      = r1.x;
    kq[16 + j].x = r0.y; kq[16 + j].y = r1.y;
    kq[32 + j].x = r0.z; kq[32 + j].y = r1.z;
    kq[48 + j].x = r0.w; kq[48 + j].y = r1.w;
  }
  #pragma unroll
  for (int j = 0; j < 64; ++j)
    asm volatile("" : "+v"(kq[j]));   // pin; block rematerialization

  // column-owned solver state (dummy zeros at a==r)
  int c0 = 32 * rg + 4 * (l & 7);
  float al[4], ap[4], yv[4], kv[4], rm2[4];
  #pragma unroll
  for (int k = 0; k < 4; ++k) {
    int a = c0 + k;
    if (a == r) {
      al[k] = 0.f; ap[k] = 0.f; yv[k] = 0.f; kv[k] = 0.f; rm2[k] = 0.f;
    } else {
      int c = a - (a > r ? 1 : 0);
      float v = alpha_init[r * NN + c];
      v = fminf(fmaxf(v, 0.f), 1.f);
      al[k] = v; ap[k] = v; yv[k] = v;
      kv[k] = 1.0f - K[r * 512 + a];
      rm2[k] = 2.0f;
    }
  }
  // publish own y slice (lanes 0-7, conflict-free) + Sy_rg (T8 shr-tree, lane 7)
  if ((l >> 3) == 0) {
    float4 y4 = {yv[0], yv[1], yv[2], yv[3]};
    *(float4*)&ytil[32 * rg + 4 * l] = y4;
  }
  {
    float sy = (yv[0] + yv[1]) + (yv[2] + yv[3]);
    sy = dpp_add<0x111, 0xf>(sy);   // row_shr:1
    sy = dpp_add<0x112, 0xf>(sy);   // row_shr:2
    sy = dpp_add<0x114, 0xf>(sy);   // row_shr:4 -> lane7 = T8
    if (l == 7) Sy_lds[rg] = sy;
  }
  __syncthreads();                   // betat + Sy + ytil visible

  float g[4];
  for (int it = 0; it < NUM_ITERS; ++it) {
    // ---- A: band matvec (R15-exact; y read is SAME-WAVE slice) ----
    const float4* yb = (const float4*)&ytil[32 * rg];
    v2f a0 = {0.f, 0.f}, a1 = {0.f, 0.f}, a2 = {0.f, 0.f}, a3 = {0.f, 0.f};
    #pragma unroll
    for (int jj = 0; jj < 8; ++jj) {
      float4 yq = yb[jj];                      // wave-broadcast b128
      v2f ylo = {yq.x, yq.y};
      v2f yhi = {yq.z, yq.w};
      pk_fma(a0, kq[2 * jj],      ylo); pk_fma(a0, kq[2 * jj + 1],      yhi);
      pk_fma(a1, kq[16 + 2 * jj], ylo); pk_fma(a1, kq[16 + 2 * jj + 1], yhi);
      pk_fma(a2, kq[32 + 2 * jj], ylo); pk_fma(a2, kq[32 + 2 * jj + 1], yhi);
      pk_fma(a3, kq[48 + 2 * jj], ylo); pk_fma(a3, kq[48 + 2 * jj + 1], yhi);
    }
    float4 accw = {a0.x + a0.y, a1.x + a1.y, a2.x + a2.y, a3.x + a3.y};
    *(float4*)&part[rg][4 * l] = accw;         // b128, conflict-free
    __syncthreads();                           // B1: partials + Sy visible

    // ---- C: per-wave reduce for OWN columns ----
    // Sv: exact wred64_dpp decomposition over the 8 per-wave partials
    float Sv = ((Sy_lds[7] + Sy_lds[6]) + (Sy_lds[5] + Sy_lds[4]))
             + ((Sy_lds[3] + Sy_lds[2]) + (Sy_lds[1] + Sy_lds[0]));
    // gr: 8 broadcast reads + R15 add4-order tree
    float p0 = part[0][r], p1 = part[1][r], p2 = part[2][r], p3 = part[3][r];
    float p4 = part[4][r], p5 = part[5][r], p6 = part[6][r], p7 = part[7][r];
    float gr = ((p0 + p1) + (p2 + p3)) + ((p4 + p5) + (p6 + p7));
    // gA for own col-quad: slice read (2-way banks = free) + band butterfly
    float4 gA = *(const float4*)&part[l >> 3][32 * rg + 4 * (l & 7)];
    gA.x = bfly8(gA.x);  gA.y = bfly8(gA.y);  gA.z = bfly8(gA.z);  gA.w = bfly8(gA.w);
    gA.x = bfly16(gA.x); gA.y = bfly16(gA.y); gA.z = bfly16(gA.z); gA.w = bfly16(gA.w);
    gA.x = bfly32(gA.x); gA.y = bfly32(gA.y); gA.z = bfly32(gA.z); gA.w = bfly32(gA.w);
    // a==r col: kv=rm2=yv=0 and gA==gr (same tree) -> g = 0 exactly
    g[0] = (gA.x - gr) - rm2[0] + kv[0] * Sv + 0.1f * yv[0];
    g[1] = (gA.y - gr) - rm2[1] + kv[1] * Sv + 0.1f * yv[1];
    g[2] = (gA.z - gr) - rm2[2] + kv[2] * Sv + 0.1f * yv[2];
    g[3] = (gA.w - gr) - rm2[3] + kv[3] * Sv + 0.1f * yv[3];
    float s = (g[0] * g[0] + g[1] * g[1]) + (g[2] * g[2] + g[3] * g[3]);
    s = dpp_add<0x111, 0xf>(s);
    s = dpp_add<0x112, 0xf>(s);
    s = dpp_add<0x114, 0xf>(s);                // lane7 = P_rg (T8)
    if (l == 7) P_lds[rg] = s;
    __syncthreads();                           // B2: n2 partials visible

    // ---- D: replicated finish + own-slice y update (no more barriers) ----
    float n2 = ((P_lds[7] + P_lds[6]) + (P_lds[5] + P_lds[4]))
             + ((P_lds[3] + P_lds[2]) + (P_lds[1] + P_lds[0]));
    float sinv = 0.001f * rsq_nr(n2);
    float beta = betat[it + 1];
    #pragma unroll
    for (int k = 0; k < 4; ++k) {
      float na = fminf(fmaxf(fmaf(-sinv, g[k], yv[k]), 0.f), 1.f);
      ap[k] = al[k];
      al[k] = na;
      yv[k] = fmaf(beta, na - ap[k], na);
    }
    if ((l >> 3) == 0) {
      float4 y4 = {yv[0], yv[1], yv[2], yv[3]};
      *(float4*)&ytil[32 * rg + 4 * l] = y4;   // same-wave RAW for next A
    }
    float sy = (yv[0] + yv[1]) + (yv[2] + yv[3]);
    sy = dpp_add<0x111, 0xf>(sy);
    sy = dpp_add<0x112, 0xf>(sy);
    sy = dpp_add<0x114, 0xf>(sy);
    if (l == 7) Sy_lds[rg] = sy;               // read after next B1 only
  }

  // epilogue: distributed state -> per-wave xor1/2/4 (exact wred_d subtree),
  // then xor-tree combine of the 8 wave partials (exact wred_d bits 3-5)
  {
    double nl = 0.0, sa = 0.0;
    int c1 = 0, cp = 0, cz = 0;
    #pragma unroll
    for (int k = 0; k < 4; ++k) {
      int a = c0 + k;
      if (a != r) {
        float kx = K[a * 512 + 256 + r];     // KnT[r, c(a)]
        nl += (double)al[k] * (double)kx;
        sa += (double)al[k];
        c1 += (al[k] == 1.0f);
        cp += (al[k] > 0.0f);
        cz += (al[k] == 0.0f);
      }
    }
    #pragma unroll
    for (int k = 1; k <= 4; k <<= 1) {
      nl += __shfl_xor(nl, k, 64);
      sa += __shfl_xor(sa, k, 64);
      c1 += __shfl_xor(c1, k, 64);
      cp += __shfl_xor(cp, k, 64);
      cz += __shfl_xor(cz, k, 64);
    }
    if (l == 0) {
      dred[0][rg] = nl; dred[1][rg] = sa;
      ired[0][rg] = c1; ired[1][rg] = cp; ired[2][rg] = cz;
    }
    __syncthreads();
    if (tid == 0) {
      double nlT = ((dred[0][0] + dred[0][1]) + (dred[0][2] + dred[0][3]))
                 + ((dred[0][4] + dred[0][5]) + (dred[0][6] + dred[0][7]));
      double saT = ((dred[1][0] + dred[1][1]) + (dred[1][2] + dred[1][3]))
                 + ((dred[1][4] + dred[1][5]) + (dred[1][6] + dred[1][7]));
      int c1T = ired[0][0] + ired[0][1] + ired[0][2] + ired[0][3]
              + ired[0][4] + ired[0][5] + ired[0][6] + ired[0][7];
      int cpT = ired[1][0] + ired[1][1] + ired[1][2] + ired[1][3]
              + ired[1][4] + ired[1][5] + ired[1][6] + ired[1][7];
      int czT = ired[2][0] + ired[2][1] + ired[2][2] + ired[2][3]
              + ired[2][4] + ired[2][5] + ired[2][6] + ired[2][7];
      neg_arr[r] = nlT;
      sa_arr[r]  = saT;
      cnt1[r] = c1T; cntp[r] = cpT; cnt0[r] = czT;
    }
  }
}

// ---------------- kernel 4: final reduction to the 6 scalar outputs ----------------
__global__ void k_fin(const double* __restrict__ pk_knt, const double* __restrict__ pos_arr,
                      const double* __restrict__ neg_arr, const double* __restrict__ sa_arr,
                      const int* __restrict__ cnt1, const int* __restrict__ cntp,
                      const int* __restrict__ cnt0, float* __restrict__ out) {
  int t = threadIdx.x;  // 256
  __shared__ double rd[16];
  __shared__ int ri[12];
  double knt = pk_knt[t];
  double pos = pos_arr[t];
  double neg = neg_arr[t];
  double pl  = sa_arr[t] * pos_arr[t];
  int a1 = cnt1[t], ap = cntp[t], a0 = cnt0[t];
  knt = wred_d(knt); pos = wred_d(pos); neg = wred_d(neg); pl = wred_d(pl);
  a1 = wred_i(a1); ap = wred_i(ap); a0 = wred_i(a0);
  int w = t >> 6;
  if ((t & 63) == 0) {
    rd[w] = knt; rd[4 + w] = pos; rd[8 + w] = neg; rd[12 + w] = pl;
    ri[w] = a1; ri[4 + w] = ap; ri[8 + w] = a0;
  }
  __syncthreads();
  if (t == 0) {
    double kntS = rd[0] + rd[1] + rd[2] + rd[3];
    double posS = rd[4] + rd[5] + rd[6] + rd[7];
    double negS = rd[8] + rd[9] + rd[10] + rd[11];
    double plS  = rd[12] + rd[13] + rd[14] + rd[15];
    int c1t = ri[0] + ri[1] + ri[2] + ri[3];
    int cpt = ri[4] + ri[5] + ri[6] + ri[7];
    int c0t = ri[8] + ri[9] + ri[10] + ri[11];
    out[0] = (float)(negS / 256.0 - plS / 256.0);
    out[1] = (float)(posS / 256.0);
    out[2] = (float)(kntS / (256.0 * 255.0));
    out[3] = (float)c1t / ((float)cpt + 1e-10f);
    out[4] = (float)c0t / 65280.0f;
    out[5] = 0.0f;
  }
}

extern "C" void kernel_launch(void* const* d_in, const int* in_sizes, int n_in,
                              void* d_out, int out_size, void* d_ws, size_t ws_size,
                              hipStream_t stream) {
  const float* z     = (const float*)d_in[0];
  const float* ainit = (const float*)d_in[1];
  char* ws = (char*)d_ws;
  double* ftrT   = (double*)ws;                       // 512 KB
  float*  K      = (float*)(ws + 524288);             // 512 KB
  double* pk_knt = (double*)(ws + 1048576);
  double* pos_a  = (double*)(ws + 1048576 + 2048);
  double* neg_a  = (double*)(ws + 1048576 + 4096);
  double* sa_a   = (double*)(ws + 1048576 + 6144);
  int* cnt1 = (int*)(ws + 1048576 + 8192);
  int* cntp = (int*)(ws + 1048576 + 8192 + 1024);
  int* cnt0 = (int*)(ws + 1048576 + 8192 + 2048);
  float* out = (float*)d_out;

  k_ftr<<<256, 128, 0, stream>>>(z, ftrT);
  k_K  <<<256, 256, 0, stream>>>(ftrT, K, pk_knt, pos_a);
  k_pgd<<<256, 512, 0, stream>>>(K, ainit, neg_a, sa_a, cnt1, cntp, cnt0);
  k_fin<<<1, 256, 0, stream>>>(pk_knt, pos_a, neg_a, sa_a, cnt1, cntp, cnt0, out);
}